// Round 3
// baseline (131.908 us; speedup 1.0000x reference)
//
#include <hip/hip_runtime.h>
#include <hip/hip_bf16.h>

// Problem constants
#define BB   16384
#define DD   128
#define HH   4
#define EE   8
#define NN   (BB*HH)   // 65536
#define OD   32
#define PT   136       // LDS row pitch in bf16 elems (128 + 8)
#define NL   32        // (expert, head) lists
#define CAP2 6144      // per-(e,h)-list capacity (mean 4096, sigma~55)

typedef __attribute__((ext_vector_type(8))) short short8;
typedef __attribute__((ext_vector_type(4))) short short4v;
typedef __attribute__((ext_vector_type(4))) float f32x4;

// RNE float -> bf16 bits
static __device__ __forceinline__ short f2bf(float v) {
    unsigned int u = __builtin_bit_cast(unsigned int, v);
    u = (u + 0x7FFFu + ((u >> 16) & 1u)) >> 16;
    return (short)u;
}
static __device__ __forceinline__ float bf2f(short b) {
    unsigned int u = ((unsigned int)(unsigned short)b) << 16;
    return __builtin_bit_cast(float, u);
}

// ---------------------------------------------------------------------------
// PREP2: everything that depends only on weights / x.
//  blocks [0,32): li=(e*4+h): A1[li] = Wq_h @ W1[e] fused matrix, bf16 MFMA,
//                 written to A1F in k2b A-fragment order; bias1[li] = bq_h@W1[e]+b1[e].
//  blocks [32,...): linear thread segments:
//    [0,262144)        xb: bf16(x)  (thread i handles 8 elems)
//    [262144,294912)   W2F frag-order conversion
//    [294912,299008)   Wkg[k][h*8+e] = sum_d Wk[k][h*128+d]*Wg[d][e]
//    [299008,299040)   bkg[h*8+e]    = sum_d bk[h*128+d]*Wg[d][e]
//    [299040,315424)   out[b] = bout[0]
//    [315424,315456)   cursors[li] = li*CAP2
// ---------------------------------------------------------------------------
__global__ __launch_bounds__(256) void prep2(
    const float* __restrict__ x, const float* __restrict__ Wq, const float* __restrict__ bq,
    const float* __restrict__ Wk, const float* __restrict__ Wg, const float* __restrict__ bk,
    const float* __restrict__ W1, const float* __restrict__ b1, const float* __restrict__ W2,
    const float* __restrict__ bout,
    short* __restrict__ xb, short* __restrict__ A1F, float* __restrict__ bias1,
    short* __restrict__ W2F, float* __restrict__ Wkg, float* __restrict__ bkg,
    float* __restrict__ out, int* __restrict__ cursors)
{
    if (blockIdx.x < 32) {
        // ---- fused A1 = Wq_h @ W1[e] (128x128x128 GEMM, one block per list) ----
        __shared__ short L[128 * PT];   // 34,816 B; reused across phases
        const int li = blockIdx.x;
        const int e = li >> 2, h = li & 3;
        const int t = threadIdx.x;
        const int wv = t >> 6, lane = t & 63, l16 = lane & 15, quad = lane >> 4;

        // phase 1: W1T staging: L[hid*PT + c] = bf16(W1[e][c][hid])
        #pragma unroll
        for (int rep = 0; rep < 16; ++rep) {
            int idx = t + rep * 256;             // 4096
            int c = idx >> 5, h4 = (idx & 31) * 4;
            float4 v = *(const float4*)(W1 + e * 16384 + c * 128 + h4);
            L[(h4 + 0) * PT + c] = f2bf(v.x);
            L[(h4 + 1) * PT + c] = f2bf(v.y);
            L[(h4 + 2) * PT + c] = f2bf(v.z);
            L[(h4 + 3) * PT + c] = f2bf(v.w);
        }
        __syncthreads();

        // A-frags (m=hid, k=c) to registers; bias1 while W1T is live
        short8 af[2][4];
        #pragma unroll
        for (int ml = 0; ml < 2; ++ml)
            #pragma unroll
            for (int ks = 0; ks < 4; ++ks)
                af[ml][ks] = *(const short8*)(L + ((wv*2 + ml)*16 + l16) * PT + ks*32 + quad*8);
        if (t < 128) {
            float s = 0.f;
            #pragma unroll 8
            for (int c = 0; c < 128; ++c)
                s += bq[h*128 + c] * bf2f(L[t * PT + c]);
            bias1[li*128 + t] = s + b1[e*128 + t];
        }
        __syncthreads();

        // phase 2: Wq tile: L[d*PT + c] = bf16(Wq[d][h*128+c])
        #pragma unroll
        for (int rep = 0; rep < 4; ++rep) {
            int idx = t + rep * 256;             // 1024
            int d = idx >> 3, c0 = (idx & 7) * 16;
            const float4* src = (const float4*)(Wq + d * 512 + h * 128 + c0);
            float4 v0 = src[0], v1 = src[1], v2 = src[2], v3 = src[3];
            short8 a, b;
            a[0]=f2bf(v0.x); a[1]=f2bf(v0.y); a[2]=f2bf(v0.z); a[3]=f2bf(v0.w);
            a[4]=f2bf(v1.x); a[5]=f2bf(v1.y); a[6]=f2bf(v1.z); a[7]=f2bf(v1.w);
            b[0]=f2bf(v2.x); b[1]=f2bf(v2.y); b[2]=f2bf(v2.z); b[3]=f2bf(v2.w);
            b[4]=f2bf(v3.x); b[5]=f2bf(v3.y); b[6]=f2bf(v3.z); b[7]=f2bf(v3.w);
            *(short8*)(L + d * PT + c0)     = a;
            *(short8*)(L + d * PT + c0 + 8) = b;
        }
        __syncthreads();

        // phase 3: MFMA — D[m=hid][n=d], K over c. wave wv: mt in {2wv, 2wv+1}
        f32x4 acc[2][8];
        #pragma unroll
        for (int ml = 0; ml < 2; ++ml)
            #pragma unroll
            for (int nt = 0; nt < 8; ++nt)
                acc[ml][nt] = (f32x4){0.f, 0.f, 0.f, 0.f};
        #pragma unroll
        for (int ks = 0; ks < 4; ++ks) {
            short8 bf[8];
            #pragma unroll
            for (int nt = 0; nt < 8; ++nt)
                bf[nt] = *(const short8*)(L + (nt*16 + l16) * PT + ks*32 + quad*8);
            #pragma unroll
            for (int ml = 0; ml < 2; ++ml)
                #pragma unroll
                for (int nt = 0; nt < 8; ++nt)
                    acc[ml][nt] = __builtin_amdgcn_mfma_f32_16x16x32_bf16(af[ml][ks], bf[nt], acc[ml][nt], 0, 0, 0);
        }
        __syncthreads();

        // phase 4: C -> LDS bf16: L[hid*PT + d]
        #pragma unroll
        for (int ml = 0; ml < 2; ++ml)
            #pragma unroll
            for (int nt = 0; nt < 8; ++nt)
                #pragma unroll
                for (int r = 0; r < 4; ++r)
                    L[((wv*2 + ml)*16 + quad*4 + r) * PT + nt*16 + l16] = f2bf(acc[ml][nt][r]);
        __syncthreads();

        // phase 5: frag-order readout -> A1F (coalesced 16B/lane)
        #pragma unroll
        for (int mt = 0; mt < 8; ++mt)
            #pragma unroll
            for (int ks = 0; ks < 4; ++ks) {
                short8 v = *(const short8*)(L + (mt*16 + l16) * PT + ks*32 + quad*8);
                *(short8*)(A1F + ((size_t)(((li*8 + mt)*4 + ks)*64 + lane)) * 8) = v;
            }
        return;
    }

    int idx = (blockIdx.x - 32) * 256 + threadIdx.x;
    if (idx < 262144) {
        const float4* x4 = (const float4*)x;
        float4 v0 = x4[idx * 2], v1 = x4[idx * 2 + 1];
        short8 s;
        s[0]=f2bf(v0.x); s[1]=f2bf(v0.y); s[2]=f2bf(v0.z); s[3]=f2bf(v0.w);
        s[4]=f2bf(v1.x); s[5]=f2bf(v1.y); s[6]=f2bf(v1.z); s[7]=f2bf(v1.w);
        *(short8*)(xb + (size_t)idx * 8) = s;
    } else if (idx < 294912) {
        int r = idx - 262144;
        int j = r & 7, lane = (r >> 3) & 63, ks = (r >> 9) & 3, mt = (r >> 11) & 1, e = r >> 12;
        int l16 = lane & 15, quad = lane >> 4;
        int m = mt * 16 + l16, k = ks * 32 + quad * 8 + j;
        W2F[r] = f2bf(W2[e * 4096 + k * 32 + m]);
    } else if (idx < 299008) {
        int r = idx - 294912;
        int k = r >> 5, col = r & 31, hh = col >> 3, e = col & 7;
        float s = 0.f;
        #pragma unroll 8
        for (int d = 0; d < 128; ++d) s += Wk[k * 512 + hh * 128 + d] * Wg[d * 8 + e];
        Wkg[k * 32 + col] = s;
    } else if (idx < 299040) {
        int r = idx - 299008;
        int hh = r >> 3, e = r & 7;
        float s = 0.f;
        #pragma unroll 8
        for (int d = 0; d < 128; ++d) s += bk[hh * 128 + d] * Wg[d * 8 + e];
        bkg[r] = s;
    } else if (idx < 315424) {
        out[idx - 299040] = bout[0];
    } else if (idx < 315456) {
        int r = idx - 315424;
        cursors[r] = r * CAP2;
    }
}

// ---------------------------------------------------------------------------
// K1gate: gating via collapsed Wkg, softmax/top-2 in registers, DIRECT binning
// into 32 fixed-capacity (expert,head) lists, aux partials per block.
// ---------------------------------------------------------------------------
__global__ __launch_bounds__(256) void k1_gate(
    const float* __restrict__ x, const float* __restrict__ Wkg, const float* __restrict__ bkg,
    float* __restrict__ wts, float* __restrict__ blkPart,
    int* __restrict__ cursors, int* __restrict__ listIdx)
{
    __shared__ float xL[64 * 129];
    __shared__ float lps[EE];
    __shared__ float lcn[EE];
    __shared__ int   lcnt[NL];
    __shared__ int   lbase[NL];

    const int t  = threadIdx.x;
    const int b0 = blockIdx.x * 64;

    if (t < EE) { lps[t] = 0.f; lcn[t] = 0.f; }
    if (t < NL) lcnt[t] = 0;

    for (int i = t; i < 2048; i += 256) {
        int r = i >> 5, c = i & 31;
        float4 v = ((const float4*)(x + (size_t)(b0 + r) * 128))[c];
        float* dst = xL + r * 129 + c * 4;
        dst[0] = v.x; dst[1] = v.y; dst[2] = v.z; dst[3] = v.w;
    }
    __syncthreads();

    const int h  = __builtin_amdgcn_readfirstlane(t >> 6);
    const int lb = t & 63;

    const f32x4* wkg4 = (const f32x4*)Wkg;
    f32x4 a0 = ((const f32x4*)bkg)[h * 2];
    f32x4 a1 = ((const f32x4*)bkg)[h * 2 + 1];

    const float* xrow = xL + lb * 129;
    #pragma unroll 4
    for (int k = 0; k < 128; ++k) {
        float xv = xrow[k];
        f32x4 w0 = wkg4[k * 8 + h * 2];
        f32x4 w1 = wkg4[k * 8 + h * 2 + 1];
        a0 += w0 * xv;
        a1 += w1 * xv;
    }

    float l[8] = {a0[0], a0[1], a0[2], a0[3], a1[0], a1[1], a1[2], a1[3]};
    float mx = l[0];
    #pragma unroll
    for (int e = 1; e < 8; ++e) mx = fmaxf(mx, l[e]);
    float p[8]; float sm = 0.f;
    #pragma unroll
    for (int e = 0; e < 8; ++e) { p[e] = __expf(l[e] - mx); sm += p[e]; }
    float isin = 1.f / sm;
    #pragma unroll
    for (int e = 0; e < 8; ++e) p[e] *= isin;

    int i1 = 0; float p1 = p[0];
    #pragma unroll
    for (int e = 1; e < 8; ++e) if (p[e] > p1) { p1 = p[e]; i1 = e; }
    int i2 = (i1 == 0) ? 1 : 0; float p2 = p[i2];
    #pragma unroll
    for (int e = 0; e < 8; ++e) if (e != i1 && p[e] > p2) { p2 = p[e]; i2 = e; }

    int n = (b0 + lb) * 4 + h;
    float rinv = 1.f / (p1 + p2);
    wts[2*n]    = p1 * rinv; wts[2*n+1]  = p2 * rinv;

    // block-local histogram slots for the two (expert,head) lists
    int li0 = i1 * 4 + h, li1 = i2 * 4 + h;
    int s0 = atomicAdd(&lcnt[li0], 1);
    int s1 = atomicAdd(&lcnt[li1], 1);

    // aux-loss partials: prob sums + top1 counts (per expert)
    #pragma unroll
    for (int e = 0; e < 8; ++e) {
        float v = p[e];
        #pragma unroll
        for (int m2 = 1; m2 < 64; m2 <<= 1) v += __shfl_xor(v, m2);
        unsigned long long m1b = __ballot(i1 == e);
        if (lb == 0) {
            atomicAdd(&lps[e], v);
            atomicAdd(&lcn[e], (float)__popcll(m1b));
        }
    }
    __syncthreads();
    if (t < NL) lbase[t] = atomicAdd(&cursors[t], lcnt[t]);
    __syncthreads();

    int q0 = lbase[li0] + s0;
    if (q0 < (li0 + 1) * CAP2) listIdx[q0] = 2*n;
    int q1 = lbase[li1] + s1;
    if (q1 < (li1 + 1) * CAP2) listIdx[q1] = 2*n + 1;

    if (t < EE) {
        float* bp = blkPart + blockIdx.x * 16;
        bp[t]     = lps[t];
        bp[8 + t] = lcn[t];
    }
}

// ---------------------------------------------------------------------------
// K2b: expert MLP via bf16 MFMA + fused head. 64 tokens of one (e,h) list.
//   GEMM1': h[hid][tok] = A1F[li] . xb^T  (128x64x128) relu+bias1 -> hL
//   GEMM2': o[od][tok]  = W2F[e]  . h^T   (32x64x128)  +b2
//   head:   out[b] += w * dot(o, Wout[h*32..h*32+32))   (atomic, 64/block)
//   h is block-uniform; aux-loss reduced by the always-idle block (95, 31).
// ---------------------------------------------------------------------------
__global__ __launch_bounds__(256) void k2b_expert(
    const short* __restrict__ xb, const short* __restrict__ A1F,
    const float* __restrict__ bias1, const short* __restrict__ W2F, const float* __restrict__ b2,
    const int* __restrict__ cursors, const int* __restrict__ listIdx,
    const float* __restrict__ wts, const float* __restrict__ Wout,
    const float* __restrict__ blkPart, float* __restrict__ out)
{
    __shared__ short tokL[64 * PT];
    __shared__ short hL[64 * PT];
    __shared__ int   ids[64];
    __shared__ float wsl[64];
    __shared__ float red[16][16];
    __shared__ float fin[16];

    const int li = blockIdx.y;
    const int e  = li >> 2;
    const int h  = li & 3;
    const int t  = threadIdx.x;

    // aux-loss reduction in a block that never has expert work
    if (blockIdx.x == gridDim.x - 1 && li == NL - 1) {
        int chunk = t >> 4, col = t & 15;
        float v = 0.f;
        for (int i = 0; i < 16; ++i) v += blkPart[(chunk * 16 + i) * 16 + col];
        red[chunk][col] = v;
        __syncthreads();
        if (t < 16) {
            float s = 0.f;
            #pragma unroll
            for (int c = 0; c < 16; ++c) s += red[c][t];
            fin[t] = s;
        }
        __syncthreads();
        if (t == 0) {
            float aux = 0.f;
            const float invN = 1.f / (float)NN;
            for (int e2 = 0; e2 < EE; ++e2) aux += (fin[8 + e2] * invN) * (fin[e2] * invN);
            out[BB] = (float)EE * aux;
        }
    }

    int cnt = cursors[li] - li * CAP2;
    if (cnt > CAP2) cnt = CAP2;
    const int off = blockIdx.x * 64;
    if (off >= cnt) return;
    const int sb  = li * CAP2 + off;
    const int nt  = min(64, cnt - off);

    if (t < 64) {
        int a = listIdx[sb + min(t, nt - 1)];
        ids[t] = a >> 3;                       // b index (a = 8b + 2h + rank)
        wsl[t] = (t < nt) ? wts[a] : 0.f;
    }
    __syncthreads();

    #pragma unroll
    for (int r = 0; r < 4; ++r) {
        int i = t + r * 256;
        int slot = i >> 4, seg = i & 15;
        short8 v = *(const short8*)(xb + (size_t)ids[slot] * 128 + seg * 8);
        *(short8*)(tokL + slot * PT + seg * 8) = v;
    }
    __syncthreads();

    const int wv   = t >> 6;
    const int lane = t & 63;
    const int l16  = lane & 15;
    const int quad = lane >> 4;

    // ---- GEMM1' ----
    f32x4 acc[2][4];
    #pragma unroll
    for (int ml = 0; ml < 2; ++ml)
        #pragma unroll
        for (int nl = 0; nl < 4; ++nl)
            acc[ml][nl] = (f32x4){0.f, 0.f, 0.f, 0.f};

    short8 af[2][4];
    #pragma unroll
    for (int ml = 0; ml < 2; ++ml)
        #pragma unroll
        for (int ks = 0; ks < 4; ++ks)
            af[ml][ks] = *(const short8*)(A1F + ((size_t)(((li*8 + wv*2 + ml)*4 + ks)*64 + lane)) * 8);

    short8 bf[4][4];
    #pragma unroll
    for (int nl = 0; nl < 4; ++nl)
        #pragma unroll
        for (int ks = 0; ks < 4; ++ks)
            bf[nl][ks] = *(const short8*)(tokL + (nl*16 + l16) * PT + ks*32 + quad*8);

    #pragma unroll
    for (int ks = 0; ks < 4; ++ks)
        #pragma unroll
        for (int ml = 0; ml < 2; ++ml)
            #pragma unroll
            for (int nl = 0; nl < 4; ++nl)
                acc[ml][nl] = __builtin_amdgcn_mfma_f32_16x16x32_bf16(af[ml][ks], bf[nl][ks], acc[ml][nl], 0, 0, 0);

    #pragma unroll
    for (int ml = 0; ml < 2; ++ml) {
        int hid0 = wv*32 + ml*16 + quad*4;
        f32x4 b1v = *(const f32x4*)(bias1 + li*128 + hid0);
        #pragma unroll
        for (int nl = 0; nl < 4; ++nl) {
            short4v hv;
            #pragma unroll
            for (int r = 0; r < 4; ++r) {
                float v = acc[ml][nl][r] + b1v[r];
                hv[r] = f2bf(fmaxf(v, 0.f));
            }
            *(short4v*)(hL + (nl*16 + l16) * PT + hid0) = hv;
        }
    }
    __syncthreads();

    // ---- GEMM2' ----
    f32x4 acc2[2];
    acc2[0] = (f32x4){0.f, 0.f, 0.f, 0.f};
    acc2[1] = (f32x4){0.f, 0.f, 0.f, 0.f};

    short8 af2[2][4];
    #pragma unroll
    for (int ml = 0; ml < 2; ++ml)
        #pragma unroll
        for (int ks = 0; ks < 4; ++ks)
            af2[ml][ks] = *(const short8*)(W2F + ((size_t)(((e*2 + ml)*4 + ks)*64 + lane)) * 8);

    short8 bf2[4];
    #pragma unroll
    for (int ks = 0; ks < 4; ++ks)
        bf2[ks] = *(const short8*)(hL + (wv*16 + l16) * PT + ks*32 + quad*8);

    #pragma unroll
    for (int ks = 0; ks < 4; ++ks)
        #pragma unroll
        for (int ml = 0; ml < 2; ++ml)
            acc2[ml] = __builtin_amdgcn_mfma_f32_16x16x32_bf16(af2[ml][ks], bf2[ks], acc2[ml], 0, 0, 0);

    // ---- fused head (h uniform per block) ----
    const int slot = wv*16 + l16;
    const int b    = ids[slot];
    float partial = 0.f;
    #pragma unroll
    for (int ml = 0; ml < 2; ++ml) {
        int od0 = ml*16 + quad*4;
        f32x4 b2v = *(const f32x4*)(b2 + e*32 + od0);
        f32x4 wv4 = *(const f32x4*)(Wout + h*32 + od0);
        #pragma unroll
        for (int r = 0; r < 4; ++r)
            partial += (acc2[ml][r] + b2v[r]) * wv4[r];
    }
    partial += __shfl_xor(partial, 16);
    partial += __shfl_xor(partial, 32);
    if (quad == 0) {
        float v = partial * wsl[slot];
        atomicAdd(&out[b], v);
    }
}

extern "C" void kernel_launch(void* const* d_in, const int* in_sizes, int n_in,
                              void* d_out, int out_size, void* d_ws, size_t ws_size,
                              hipStream_t stream) {
    (void)in_sizes; (void)n_in; (void)out_size; (void)ws_size;
    const float* x    = (const float*)d_in[0];
    const float* Wq   = (const float*)d_in[1];
    const float* bq   = (const float*)d_in[2];
    const float* Wk   = (const float*)d_in[3];
    const float* bk   = (const float*)d_in[4];
    const float* Wg   = (const float*)d_in[5];
    const float* W1   = (const float*)d_in[6];
    const float* b1   = (const float*)d_in[7];
    const float* W2   = (const float*)d_in[8];
    const float* b2   = (const float*)d_in[9];
    const float* Wout = (const float*)d_in[10];
    const float* bout = (const float*)d_in[11];
    float* out = (float*)d_out;

    char* ws = (char*)d_ws;
    short* xb       = (short*)(ws + 0);              //  4,194,304
    float* wts      = (float*)(ws + 4194304);        //    524,288
    int*   listIdx  = (int*)  (ws + 4718592);        //    786,432 (32*CAP2*4)
    short* A1F      = (short*)(ws + 5505024);        //  1,048,576
    short* W2F      = (short*)(ws + 6553600);        //     65,536
    float* Wkg      = (float*)(ws + 6619136);        //     16,384
    float* bkg      = (float*)(ws + 6635520);        //        128
    float* bias1    = (float*)(ws + 6635648);        //     16,384
    float* blkPart  = (float*)(ws + 6652032);        //     16,384
    int*   cursors  = (int*)  (ws + 6668416);        //        128

    prep2<<<1265, 256, 0, stream>>>(x, Wq, bq, Wk, Wg, bk, W1, b1, W2, bout,
                                    xb, A1F, bias1, W2F, Wkg, bkg, out, cursors);
    k1_gate<<<256, 256, 0, stream>>>(x, Wkg, bkg, wts, blkPart, cursors, listIdx);
    k2b_expert<<<dim3(CAP2/64, NL), 256, 0, stream>>>(xb, A1F, bias1, W2F, b2,
                                    cursors, listIdx, wts, Wout, blkPart, out);
}

// Round 6
// 126.485 us; speedup vs baseline: 1.0429x; 1.0429x over previous
//
#include <hip/hip_runtime.h>
#include <hip/hip_bf16.h>

// Problem constants
#define BB   16384
#define DD   128
#define HH   4
#define EE   8
#define NN   (BB*HH)   // 65536
#define OD   32
#define PT   136       // LDS row pitch in bf16 elems (128 + 8)
#define NL   32        // (expert, head) lists
#define CAP2 6144      // per-(e,h)-list capacity (mean 4096, sigma~55)

typedef __attribute__((ext_vector_type(8))) short short8;
typedef __attribute__((ext_vector_type(4))) short short4v;
typedef __attribute__((ext_vector_type(4))) float f32x4;

// RNE float -> bf16 bits
static __device__ __forceinline__ short f2bf(float v) {
    unsigned int u = __builtin_bit_cast(unsigned int, v);
    u = (u + 0x7FFFu + ((u >> 16) & 1u)) >> 16;
    return (short)u;
}
static __device__ __forceinline__ float bf2f(short b) {
    unsigned int u = ((unsigned int)(unsigned short)b) << 16;
    return __builtin_bit_cast(float, u);
}

// ---------------------------------------------------------------------------
// L1 PREP_TINY: only what the gate needs (+tiny inits). 81 blocks, ~1.5us.
//   [0,4096)      Wkg[k][hh*8+e] = sum_d Wk[k][hh*128+d]*Wg[d][e]
//   [4096,4128)   bkg[hh*8+e]    = sum_d bk[hh*128+d]*Wg[d][e]
//   [4128,20512)  out[b] = bout[0]
//   [20512,20544) cursors[li] = li*CAP2
// ---------------------------------------------------------------------------
__global__ __launch_bounds__(256) void prep_tiny(
    const float* __restrict__ Wk, const float* __restrict__ Wg,
    const float* __restrict__ bk, const float* __restrict__ bout,
    float* __restrict__ Wkg, float* __restrict__ bkg,
    float* __restrict__ out, int* __restrict__ cursors)
{
    int idx = blockIdx.x * 256 + threadIdx.x;
    if (idx < 4096) {
        int k = idx >> 5, col = idx & 31, hh = col >> 3, e = col & 7;
        float s = 0.f;
        #pragma unroll 8
        for (int d = 0; d < 128; ++d) s += Wk[k * 512 + hh * 128 + d] * Wg[d * 8 + e];
        Wkg[k * 32 + col] = s;
    } else if (idx < 4128) {
        int r = idx - 4096;
        int hh = r >> 3, e = r & 7;
        float s = 0.f;
        #pragma unroll 8
        for (int d = 0; d < 128; ++d) s += bk[hh * 128 + d] * Wg[d * 8 + e];
        bkg[r] = s;
    } else if (idx < 20512) {
        out[idx - 4128] = bout[0];
    } else if (idx < 20544) {
        int r = idx - 20512;
        cursors[r] = r * CAP2;
    }
}

// ---------------------------------------------------------------------------
// L2 MID: three independent block roles (no cross-block deps):
//   blocks [0,256):    gate (R3-verbatim): Wkg gate GEMM, softmax/top-2,
//                      cursor binning into listIdx, aux partials.
//   blocks [256,288):  A1[li] = Wq_h @ W1[e] fused matrices (R3-verbatim).
//   blocks [288,1184): conversions, 1152 segs: xb=bf16(x) [0,1024),
//                      W2F frag-order [1024,1152).
// ---------------------------------------------------------------------------
__global__ __launch_bounds__(256) void mid(
    const float* __restrict__ x, const float* __restrict__ Wq, const float* __restrict__ bq,
    const float* __restrict__ W1, const float* __restrict__ b1, const float* __restrict__ W2,
    const float* __restrict__ Wkg, const float* __restrict__ bkg,
    short* __restrict__ xb, short* __restrict__ A1F, float* __restrict__ bias1,
    short* __restrict__ W2F, float* __restrict__ wts, float* __restrict__ blkPart,
    int* __restrict__ cursors, int* __restrict__ listIdx)
{
    __shared__ __align__(16) char smemU[34816];   // union: gate xL (33024) / A1 L (34816)
    __shared__ float lps[EE];
    __shared__ float lcn[EE];
    __shared__ int   lcnt[NL];
    __shared__ int   lbase[NL];

    const int blk = blockIdx.x;
    const int t   = threadIdx.x;

    if (blk < 256) {
        // =================== gate path (R3-verbatim) ===================
        float* xL = (float*)smemU;                // [64][129]
        const int b0 = blk * 64;

        if (t < EE) { lps[t] = 0.f; lcn[t] = 0.f; }
        if (t < NL) lcnt[t] = 0;

        for (int i = t; i < 2048; i += 256) {
            int r = i >> 5, c = i & 31;
            float4 v = ((const float4*)(x + (size_t)(b0 + r) * 128))[c];
            float* dst = xL + r * 129 + c * 4;
            dst[0] = v.x; dst[1] = v.y; dst[2] = v.z; dst[3] = v.w;
        }
        __syncthreads();

        const int h  = __builtin_amdgcn_readfirstlane(t >> 6);
        const int lb = t & 63;

        const f32x4* wkg4 = (const f32x4*)Wkg;
        f32x4 a0 = ((const f32x4*)bkg)[h * 2];
        f32x4 a1 = ((const f32x4*)bkg)[h * 2 + 1];

        const float* xrow = xL + lb * 129;
        #pragma unroll 4
        for (int k = 0; k < 128; ++k) {
            float xv = xrow[k];
            f32x4 w0 = wkg4[k * 8 + h * 2];
            f32x4 w1 = wkg4[k * 8 + h * 2 + 1];
            a0 += w0 * xv;
            a1 += w1 * xv;
        }

        float l[8] = {a0[0], a0[1], a0[2], a0[3], a1[0], a1[1], a1[2], a1[3]};
        float mx = l[0];
        #pragma unroll
        for (int e = 1; e < 8; ++e) mx = fmaxf(mx, l[e]);
        float p[8]; float sm = 0.f;
        #pragma unroll
        for (int e = 0; e < 8; ++e) { p[e] = __expf(l[e] - mx); sm += p[e]; }
        float isin = 1.f / sm;
        #pragma unroll
        for (int e = 0; e < 8; ++e) p[e] *= isin;

        int i1 = 0; float p1 = p[0];
        #pragma unroll
        for (int e = 1; e < 8; ++e) if (p[e] > p1) { p1 = p[e]; i1 = e; }
        int i2 = (i1 == 0) ? 1 : 0; float p2 = p[i2];
        #pragma unroll
        for (int e = 0; e < 8; ++e) if (e != i1 && p[e] > p2) { p2 = p[e]; i2 = e; }

        int n = (b0 + lb) * 4 + h;
        float rinv = 1.f / (p1 + p2);
        wts[2*n]    = p1 * rinv; wts[2*n+1]  = p2 * rinv;

        int li0 = i1 * 4 + h, li1 = i2 * 4 + h;
        int s0 = atomicAdd(&lcnt[li0], 1);
        int s1 = atomicAdd(&lcnt[li1], 1);

        #pragma unroll
        for (int e = 0; e < 8; ++e) {
            float v = p[e];
            #pragma unroll
            for (int m2 = 1; m2 < 64; m2 <<= 1) v += __shfl_xor(v, m2);
            unsigned long long m1b = __ballot(i1 == e);
            if (lb == 0) {
                atomicAdd(&lps[e], v);
                atomicAdd(&lcn[e], (float)__popcll(m1b));
            }
        }
        __syncthreads();
        if (t < NL) lbase[t] = atomicAdd(&cursors[t], lcnt[t]);
        __syncthreads();

        int q0 = lbase[li0] + s0;
        if (q0 < (li0 + 1) * CAP2) listIdx[q0] = 2*n;
        int q1 = lbase[li1] + s1;
        if (q1 < (li1 + 1) * CAP2) listIdx[q1] = 2*n + 1;

        if (t < EE) {
            float* bp = blkPart + blk * 16;
            bp[t]     = lps[t];
            bp[8 + t] = lcn[t];
        }
    } else if (blk < 288) {
        // =================== A1 fused-weight GEMM path (R3-verbatim) ===================
        short* L = (short*)smemU;                 // 128*PT shorts = 34816 B
        const int li = blk - 256;
        const int e = li >> 2, h = li & 3;
        const int wv = t >> 6, lane = t & 63, l16 = lane & 15, quad = lane >> 4;

        // phase 1: W1T staging: L[hid*PT + c] = bf16(W1[e][c][hid])
        #pragma unroll
        for (int rep = 0; rep < 16; ++rep) {
            int idx = t + rep * 256;              // 4096
            int c = idx >> 5, h4 = (idx & 31) * 4;
            float4 v = *(const float4*)(W1 + e * 16384 + c * 128 + h4);
            L[(h4 + 0) * PT + c] = f2bf(v.x);
            L[(h4 + 1) * PT + c] = f2bf(v.y);
            L[(h4 + 2) * PT + c] = f2bf(v.z);
            L[(h4 + 3) * PT + c] = f2bf(v.w);
        }
        __syncthreads();

        short8 af[2][4];
        #pragma unroll
        for (int ml = 0; ml < 2; ++ml)
            #pragma unroll
            for (int ks = 0; ks < 4; ++ks)
                af[ml][ks] = *(const short8*)(L + ((wv*2 + ml)*16 + l16) * PT + ks*32 + quad*8);
        if (t < 128) {
            float s = 0.f;
            #pragma unroll 8
            for (int c = 0; c < 128; ++c)
                s += bq[h*128 + c] * bf2f(L[t * PT + c]);
            bias1[li*128 + t] = s + b1[e*128 + t];
        }
        __syncthreads();

        // phase 2: Wq tile: L[d*PT + c] = bf16(Wq[d][h*128+c])
        #pragma unroll
        for (int rep = 0; rep < 4; ++rep) {
            int idx = t + rep * 256;              // 1024
            int d = idx >> 3, c0 = (idx & 7) * 16;
            const float4* src = (const float4*)(Wq + d * 512 + h * 128 + c0);
            float4 v0 = src[0], v1 = src[1], v2 = src[2], v3 = src[3];
            short8 a, b;
            a[0]=f2bf(v0.x); a[1]=f2bf(v0.y); a[2]=f2bf(v0.z); a[3]=f2bf(v0.w);
            a[4]=f2bf(v1.x); a[5]=f2bf(v1.y); a[6]=f2bf(v1.z); a[7]=f2bf(v1.w);
            b[0]=f2bf(v2.x); b[1]=f2bf(v2.y); b[2]=f2bf(v2.z); b[3]=f2bf(v2.w);
            b[4]=f2bf(v3.x); b[5]=f2bf(v3.y); b[6]=f2bf(v3.z); b[7]=f2bf(v3.w);
            *(short8*)(L + d * PT + c0)     = a;
            *(short8*)(L + d * PT + c0 + 8) = b;
        }
        __syncthreads();

        // phase 3: MFMA — D[m=hid][n=d], K over c
        f32x4 acc[2][8];
        #pragma unroll
        for (int ml = 0; ml < 2; ++ml)
            #pragma unroll
            for (int nt2 = 0; nt2 < 8; ++nt2)
                acc[ml][nt2] = (f32x4){0.f, 0.f, 0.f, 0.f};
        #pragma unroll
        for (int ks = 0; ks < 4; ++ks) {
            short8 bfr[8];
            #pragma unroll
            for (int nt2 = 0; nt2 < 8; ++nt2)
                bfr[nt2] = *(const short8*)(L + (nt2*16 + l16) * PT + ks*32 + quad*8);
            #pragma unroll
            for (int ml = 0; ml < 2; ++ml)
                #pragma unroll
                for (int nt2 = 0; nt2 < 8; ++nt2)
                    acc[ml][nt2] = __builtin_amdgcn_mfma_f32_16x16x32_bf16(af[ml][ks], bfr[nt2], acc[ml][nt2], 0, 0, 0);
        }
        __syncthreads();

        // phase 4: C -> LDS bf16: L[hid*PT + d]
        #pragma unroll
        for (int ml = 0; ml < 2; ++ml)
            #pragma unroll
            for (int nt2 = 0; nt2 < 8; ++nt2)
                #pragma unroll
                for (int r = 0; r < 4; ++r)
                    L[((wv*2 + ml)*16 + quad*4 + r) * PT + nt2*16 + l16] = f2bf(acc[ml][nt2][r]);
        __syncthreads();

        // phase 5: frag-order readout -> A1F
        #pragma unroll
        for (int mt = 0; mt < 8; ++mt)
            #pragma unroll
            for (int ks = 0; ks < 4; ++ks) {
                short8 v = *(const short8*)(L + (mt*16 + l16) * PT + ks*32 + quad*8);
                *(short8*)(A1F + ((size_t)(((li*8 + mt)*4 + ks)*64 + lane)) * 8) = v;
            }
    } else {
        // =================== conversion path ===================
        for (int s = blk - 288; s < 1152; s += 896) {
            if (s < 1024) {
                int idx = s * 256 + t;            // [0,262144)
                const float4* x4 = (const float4*)x;
                float4 v0 = x4[idx * 2], v1 = x4[idx * 2 + 1];
                short8 sv;
                sv[0]=f2bf(v0.x); sv[1]=f2bf(v0.y); sv[2]=f2bf(v0.z); sv[3]=f2bf(v0.w);
                sv[4]=f2bf(v1.x); sv[5]=f2bf(v1.y); sv[6]=f2bf(v1.z); sv[7]=f2bf(v1.w);
                *(short8*)(xb + (size_t)idx * 8) = sv;
            } else {
                int r = (s - 1024) * 256 + t;     // [0,32768)
                int j = r & 7, lane = (r >> 3) & 63, ks = (r >> 9) & 3, mt = (r >> 11) & 1, e = r >> 12;
                int l16 = lane & 15, quad = lane >> 4;
                int m = mt * 16 + l16, k = ks * 32 + quad * 8 + j;
                W2F[r] = f2bf(W2[e * 4096 + k * 32 + m]);
            }
        }
    }
}

// ---------------------------------------------------------------------------
// L3 K2B (R3-verbatim): expert MLP via bf16 MFMA + fused head.
//   GEMM1': h[hid][tok] = A1F[li] . xb^T  (128x64x128) relu+bias1 -> hL
//   GEMM2': o[od][tok]  = W2F[e]  . h^T   (32x64x128)  +b2
//   head:   out[b] += w * dot(o, Wout[h*32..))   (atomic)
// ---------------------------------------------------------------------------
__global__ __launch_bounds__(256) void k2b_expert(
    const short* __restrict__ xb, const short* __restrict__ A1F,
    const float* __restrict__ bias1, const short* __restrict__ W2F, const float* __restrict__ b2,
    const int* __restrict__ cursors, const int* __restrict__ listIdx,
    const float* __restrict__ wts, const float* __restrict__ Wout,
    const float* __restrict__ blkPart, float* __restrict__ out)
{
    __shared__ short tokL[64 * PT];
    __shared__ short hL[64 * PT];
    __shared__ int   ids[64];
    __shared__ float wsl[64];
    __shared__ float red[16][16];
    __shared__ float fin[16];

    const int li = blockIdx.y;
    const int e  = li >> 2;
    const int h  = li & 3;
    const int t  = threadIdx.x;

    if (blockIdx.x == gridDim.x - 1 && li == NL - 1) {
        int chunk = t >> 4, col = t & 15;
        float v = 0.f;
        for (int i = 0; i < 16; ++i) v += blkPart[(chunk * 16 + i) * 16 + col];
        red[chunk][col] = v;
        __syncthreads();
        if (t < 16) {
            float s = 0.f;
            #pragma unroll
            for (int c = 0; c < 16; ++c) s += red[c][t];
            fin[t] = s;
        }
        __syncthreads();
        if (t == 0) {
            float aux = 0.f;
            const float invN = 1.f / (float)NN;
            for (int e2 = 0; e2 < EE; ++e2) aux += (fin[8 + e2] * invN) * (fin[e2] * invN);
            out[BB] = (float)EE * aux;
        }
    }

    int cnt = cursors[li] - li * CAP2;
    if (cnt > CAP2) cnt = CAP2;
    const int off = blockIdx.x * 64;
    if (off >= cnt) return;
    const int sb  = li * CAP2 + off;
    const int nt  = min(64, cnt - off);

    if (t < 64) {
        int a = listIdx[sb + min(t, nt - 1)];
        ids[t] = a >> 3;                       // b index (a = 8b + 2h + rank)
        wsl[t] = (t < nt) ? wts[a] : 0.f;
    }
    __syncthreads();

    #pragma unroll
    for (int r = 0; r < 4; ++r) {
        int i = t + r * 256;
        int slot = i >> 4, seg = i & 15;
        short8 v = *(const short8*)(xb + (size_t)ids[slot] * 128 + seg * 8);
        *(short8*)(tokL + slot * PT + seg * 8) = v;
    }
    __syncthreads();

    const int wv   = t >> 6;
    const int lane = t & 63;
    const int l16  = lane & 15;
    const int quad = lane >> 4;

    // ---- GEMM1' ----
    f32x4 acc[2][4];
    #pragma unroll
    for (int ml = 0; ml < 2; ++ml)
        #pragma unroll
        for (int nl = 0; nl < 4; ++nl)
            acc[ml][nl] = (f32x4){0.f, 0.f, 0.f, 0.f};

    short8 af[2][4];
    #pragma unroll
    for (int ml = 0; ml < 2; ++ml)
        #pragma unroll
        for (int ks = 0; ks < 4; ++ks)
            af[ml][ks] = *(const short8*)(A1F + ((size_t)(((li*8 + wv*2 + ml)*4 + ks)*64 + lane)) * 8);

    short8 bfr[4][4];
    #pragma unroll
    for (int nl = 0; nl < 4; ++nl)
        #pragma unroll
        for (int ks = 0; ks < 4; ++ks)
            bfr[nl][ks] = *(const short8*)(tokL + (nl*16 + l16) * PT + ks*32 + quad*8);

    #pragma unroll
    for (int ks = 0; ks < 4; ++ks)
        #pragma unroll
        for (int ml = 0; ml < 2; ++ml)
            #pragma unroll
            for (int nl = 0; nl < 4; ++nl)
                acc[ml][nl] = __builtin_amdgcn_mfma_f32_16x16x32_bf16(af[ml][ks], bfr[nl][ks], acc[ml][nl], 0, 0, 0);

    #pragma unroll
    for (int ml = 0; ml < 2; ++ml) {
        int hid0 = wv*32 + ml*16 + quad*4;
        f32x4 b1v = *(const f32x4*)(bias1 + li*128 + hid0);
        #pragma unroll
        for (int nl = 0; nl < 4; ++nl) {
            short4v hv;
            #pragma unroll
            for (int r = 0; r < 4; ++r) {
                float v = acc[ml][nl][r] + b1v[r];
                hv[r] = f2bf(fmaxf(v, 0.f));
            }
            *(short4v*)(hL + (nl*16 + l16) * PT + hid0) = hv;
        }
    }
    __syncthreads();

    // ---- GEMM2' ----
    f32x4 acc2[2];
    acc2[0] = (f32x4){0.f, 0.f, 0.f, 0.f};
    acc2[1] = (f32x4){0.f, 0.f, 0.f, 0.f};

    short8 af2[2][4];
    #pragma unroll
    for (int ml = 0; ml < 2; ++ml)
        #pragma unroll
        for (int ks = 0; ks < 4; ++ks)
            af2[ml][ks] = *(const short8*)(W2F + ((size_t)(((e*2 + ml)*4 + ks)*64 + lane)) * 8);

    short8 bf2[4];
    #pragma unroll
    for (int ks = 0; ks < 4; ++ks)
        bf2[ks] = *(const short8*)(hL + (wv*16 + l16) * PT + ks*32 + quad*8);

    #pragma unroll
    for (int ks = 0; ks < 4; ++ks)
        #pragma unroll
        for (int ml = 0; ml < 2; ++ml)
            acc2[ml] = __builtin_amdgcn_mfma_f32_16x16x32_bf16(af2[ml][ks], bf2[ks], acc2[ml], 0, 0, 0);

    // ---- fused head (h uniform per block) ----
    const int slot = wv*16 + l16;
    const int b    = ids[slot];
    float partial = 0.f;
    #pragma unroll
    for (int ml = 0; ml < 2; ++ml) {
        int od0 = ml*16 + quad*4;
        f32x4 b2v = *(const f32x4*)(b2 + e*32 + od0);
        f32x4 wv4 = *(const f32x4*)(Wout + h*32 + od0);
        #pragma unroll
        for (int r = 0; r < 4; ++r)
            partial += (acc2[ml][r] + b2v[r]) * wv4[r];
    }
    partial += __shfl_xor(partial, 16);
    partial += __shfl_xor(partial, 32);
    if (quad == 0) {
        float v = partial * wsl[slot];
        atomicAdd(&out[b], v);
    }
}

extern "C" void kernel_launch(void* const* d_in, const int* in_sizes, int n_in,
                              void* d_out, int out_size, void* d_ws, size_t ws_size,
                              hipStream_t stream) {
    (void)in_sizes; (void)n_in; (void)out_size; (void)ws_size;
    const float* x    = (const float*)d_in[0];
    const float* Wq   = (const float*)d_in[1];
    const float* bq   = (const float*)d_in[2];
    const float* Wk   = (const float*)d_in[3];
    const float* bk   = (const float*)d_in[4];
    const float* Wg   = (const float*)d_in[5];
    const float* W1   = (const float*)d_in[6];
    const float* b1   = (const float*)d_in[7];
    const float* W2   = (const float*)d_in[8];
    const float* b2   = (const float*)d_in[9];
    const float* Wout = (const float*)d_in[10];
    const float* bout = (const float*)d_in[11];
    float* out = (float*)d_out;

    char* ws = (char*)d_ws;
    short* xb       = (short*)(ws + 0);              //  4,194,304
    float* wts      = (float*)(ws + 4194304);        //    524,288
    int*   listIdx  = (int*)  (ws + 4718592);        //    786,432 (32*CAP2*4)
    short* A1F      = (short*)(ws + 5505024);        //  1,048,576
    short* W2F      = (short*)(ws + 6553600);        //     65,536
    float* Wkg      = (float*)(ws + 6619136);        //     16,384
    float* bkg      = (float*)(ws + 6635520);        //        128
    float* bias1    = (float*)(ws + 6635648);        //     16,384
    float* blkPart  = (float*)(ws + 6652032);        //     16,384
    int*   cursors  = (int*)  (ws + 6668416);        //        128

    prep_tiny<<<81, 256, 0, stream>>>(Wk, Wg, bk, bout, Wkg, bkg, out, cursors);
    mid<<<1184, 256, 0, stream>>>(x, Wq, bq, W1, b1, W2, Wkg, bkg,
                                  xb, A1F, bias1, W2F, wts, blkPart, cursors, listIdx);
    k2b_expert<<<dim3(96, NL), 256, 0, stream>>>(xb, A1F, bias1, W2F, b2,
                                  cursors, listIdx, wts, Wout, blkPart, out);
}

// Round 7
// 124.860 us; speedup vs baseline: 1.0564x; 1.0130x over previous
//
#include <hip/hip_runtime.h>
#include <hip/hip_bf16.h>

// Problem constants
#define BB   16384
#define DD   128
#define HH   4
#define EE   8
#define NN   (BB*HH)   // 65536
#define OD   32
#define PT   136       // LDS row pitch in bf16 elems (128 + 8)
#define NL   32        // (expert, head) lists
#define CAP2 6144      // per-(e,h)-list capacity (mean 4096, sigma~55)

typedef __attribute__((ext_vector_type(8))) short short8;
typedef __attribute__((ext_vector_type(4))) short short4v;
typedef __attribute__((ext_vector_type(4))) float f32x4;

// RNE float -> bf16 bits
static __device__ __forceinline__ short f2bf(float v) {
    unsigned int u = __builtin_bit_cast(unsigned int, v);
    u = (u + 0x7FFFu + ((u >> 16) & 1u)) >> 16;
    return (short)u;
}
static __device__ __forceinline__ float bf2f(short b) {
    unsigned int u = ((unsigned int)(unsigned short)b) << 16;
    return __builtin_bit_cast(float, u);
}

// ---------------------------------------------------------------------------
// L1 MID: three independent block roles (no cross-block deps):
//   blocks [0,256):    gate. Stages Wg to LDS, computes collapsed Wkg/bkg
//                      REDUNDANTLY per block (512 FMA/thread, Wk from L2),
//                      then gate GEMM, softmax/top-2, cursor binning
//                      (cursors pre-zeroed by hipMemsetAsync; bases folded
//                      as li*CAP2 + relative), aux partials.
//   blocks [256,288):  A1[li] = Wq_h @ W1[e] fused matrices (R6-verbatim).
//   blocks [288,1184): conversions, 1216 segs: xb=bf16(x) [0,1024),
//                      W2F frag-order [1024,1152), out-init [1152,1216).
// ---------------------------------------------------------------------------
__global__ __launch_bounds__(256) void mid(
    const float* __restrict__ x, const float* __restrict__ Wq, const float* __restrict__ bq,
    const float* __restrict__ Wk, const float* __restrict__ Wg, const float* __restrict__ bk,
    const float* __restrict__ W1, const float* __restrict__ b1, const float* __restrict__ W2,
    const float* __restrict__ bout,
    short* __restrict__ xb, short* __restrict__ A1F, float* __restrict__ bias1,
    short* __restrict__ W2F, float* __restrict__ wts, float* __restrict__ blkPart,
    int* __restrict__ cursors, int* __restrict__ listIdx, float* __restrict__ out)
{
    __shared__ __align__(16) char smemU[53760];   // gate: xL 33024 + wg4 4096 + wkgL 16384 + bkgL 128 = 53632; A1: 34816
    __shared__ float lps[EE];
    __shared__ float lcn[EE];
    __shared__ int   lcnt[NL];
    __shared__ int   lbase[NL];

    const int blk = blockIdx.x;
    const int t   = threadIdx.x;

    if (blk < 256) {
        // =================== gate path ===================
        float* xL   = (float*)smemU;                 // [64][129] fp32 = 33024 B
        f32x4* wg4  = (f32x4*)(smemU + 33024);       // Wg [128][8] f32 = 4096 B (2 f32x4 per d)
        f32x4* wkgL = (f32x4*)(smemU + 37120);       // collapsed Wkg [128][32] f32 = 16384 B
        float* bkgL = (float*)(smemU + 53504);       // 32 floats
        const int b0 = blk * 64;

        if (t < EE) { lps[t] = 0.f; lcn[t] = 0.f; }
        if (t < NL) lcnt[t] = 0;

        // stage Wg (1024 floats, [d][e] layout preserved)
        ((float4*)wg4)[t] = ((const float4*)Wg)[t];

        // stage x tile (fp32)
        for (int i = t; i < 2048; i += 256) {
            int r = i >> 5, c = i & 31;
            float4 v = ((const float4*)(x + (size_t)(b0 + r) * 128))[c];
            float* dst = xL + r * 129 + c * 4;
            dst[0] = v.x; dst[1] = v.y; dst[2] = v.z; dst[3] = v.w;
        }
        __syncthreads();

        // redundant Wkg collapse: each thread handles 2 (k,hh) pairs
        #pragma unroll
        for (int rep = 0; rep < 2; ++rep) {
            int pi = t + rep * 256;                  // [0,512) = k*4 + hh
            int k = pi >> 2, hh = pi & 3;
            f32x4 a0 = (f32x4){0.f,0.f,0.f,0.f}, a1v = (f32x4){0.f,0.f,0.f,0.f};
            const float* wkrow = Wk + k * 512 + hh * 128;
            #pragma unroll 4
            for (int d0 = 0; d0 < 128; d0 += 4) {
                float4 w = *(const float4*)(wkrow + d0);
                a0 += wg4[(d0+0)*2]   * w.x;  a1v += wg4[(d0+0)*2+1] * w.x;
                a0 += wg4[(d0+1)*2]   * w.y;  a1v += wg4[(d0+1)*2+1] * w.y;
                a0 += wg4[(d0+2)*2]   * w.z;  a1v += wg4[(d0+2)*2+1] * w.z;
                a0 += wg4[(d0+3)*2]   * w.w;  a1v += wg4[(d0+3)*2+1] * w.w;
            }
            wkgL[k*8 + hh*2]     = a0;
            wkgL[k*8 + hh*2 + 1] = a1v;
        }
        if (t < 32) {
            int hh = t >> 3, e = t & 7;
            const float* wgf = (const float*)wg4;
            float s = 0.f;
            #pragma unroll 8
            for (int d = 0; d < 128; ++d) s += bk[hh*128 + d] * wgf[d*8 + e];
            bkgL[t] = s;
        }
        __syncthreads();

        const int h  = __builtin_amdgcn_readfirstlane(t >> 6);
        const int lb = t & 63;

        f32x4 a0 = ((const f32x4*)bkgL)[h * 2];
        f32x4 a1 = ((const f32x4*)bkgL)[h * 2 + 1];

        const float* xrow = xL + lb * 129;
        #pragma unroll 4
        for (int k = 0; k < 128; ++k) {
            float xv = xrow[k];
            f32x4 w0 = wkgL[k * 8 + h * 2];
            f32x4 w1 = wkgL[k * 8 + h * 2 + 1];
            a0 += w0 * xv;
            a1 += w1 * xv;
        }

        float l[8] = {a0[0], a0[1], a0[2], a0[3], a1[0], a1[1], a1[2], a1[3]};
        float mx = l[0];
        #pragma unroll
        for (int e = 1; e < 8; ++e) mx = fmaxf(mx, l[e]);
        float p[8]; float sm = 0.f;
        #pragma unroll
        for (int e = 0; e < 8; ++e) { p[e] = __expf(l[e] - mx); sm += p[e]; }
        float isin = 1.f / sm;
        #pragma unroll
        for (int e = 0; e < 8; ++e) p[e] *= isin;

        int i1 = 0; float p1 = p[0];
        #pragma unroll
        for (int e = 1; e < 8; ++e) if (p[e] > p1) { p1 = p[e]; i1 = e; }
        int i2 = (i1 == 0) ? 1 : 0; float p2 = p[i2];
        #pragma unroll
        for (int e = 0; e < 8; ++e) if (e != i1 && p[e] > p2) { p2 = p[e]; i2 = e; }

        int n = (b0 + lb) * 4 + h;
        float rinv = 1.f / (p1 + p2);
        wts[2*n]    = p1 * rinv; wts[2*n+1]  = p2 * rinv;

        int li0 = i1 * 4 + h, li1 = i2 * 4 + h;
        int s0 = atomicAdd(&lcnt[li0], 1);
        int s1 = atomicAdd(&lcnt[li1], 1);

        #pragma unroll
        for (int e = 0; e < 8; ++e) {
            float v = p[e];
            #pragma unroll
            for (int m2 = 1; m2 < 64; m2 <<= 1) v += __shfl_xor(v, m2);
            unsigned long long m1b = __ballot(i1 == e);
            if (lb == 0) {
                atomicAdd(&lps[e], v);
                atomicAdd(&lcn[e], (float)__popcll(m1b));
            }
        }
        __syncthreads();
        if (t < NL) lbase[t] = atomicAdd(&cursors[t], lcnt[t]);   // zero-based (memset)
        __syncthreads();

        int q0 = li0 * CAP2 + lbase[li0] + s0;
        if (q0 < (li0 + 1) * CAP2) listIdx[q0] = 2*n;
        int q1 = li1 * CAP2 + lbase[li1] + s1;
        if (q1 < (li1 + 1) * CAP2) listIdx[q1] = 2*n + 1;

        if (t < EE) {
            float* bp = blkPart + blk * 16;
            bp[t]     = lps[t];
            bp[8 + t] = lcn[t];
        }
    } else if (blk < 288) {
        // =================== A1 fused-weight GEMM path (R6-verbatim) ===================
        short* L = (short*)smemU;                 // 128*PT shorts = 34816 B
        const int li = blk - 256;
        const int e = li >> 2, h = li & 3;
        const int wv = t >> 6, lane = t & 63, l16 = lane & 15, quad = lane >> 4;

        // phase 1: W1T staging: L[hid*PT + c] = bf16(W1[e][c][hid])
        #pragma unroll
        for (int rep = 0; rep < 16; ++rep) {
            int idx = t + rep * 256;              // 4096
            int c = idx >> 5, h4 = (idx & 31) * 4;
            float4 v = *(const float4*)(W1 + e * 16384 + c * 128 + h4);
            L[(h4 + 0) * PT + c] = f2bf(v.x);
            L[(h4 + 1) * PT + c] = f2bf(v.y);
            L[(h4 + 2) * PT + c] = f2bf(v.z);
            L[(h4 + 3) * PT + c] = f2bf(v.w);
        }
        __syncthreads();

        short8 af[2][4];
        #pragma unroll
        for (int ml = 0; ml < 2; ++ml)
            #pragma unroll
            for (int ks = 0; ks < 4; ++ks)
                af[ml][ks] = *(const short8*)(L + ((wv*2 + ml)*16 + l16) * PT + ks*32 + quad*8);
        if (t < 128) {
            float s = 0.f;
            #pragma unroll 8
            for (int c = 0; c < 128; ++c)
                s += bq[h*128 + c] * bf2f(L[t * PT + c]);
            bias1[li*128 + t] = s + b1[e*128 + t];
        }
        __syncthreads();

        // phase 2: Wq tile: L[d*PT + c] = bf16(Wq[d][h*128+c])
        #pragma unroll
        for (int rep = 0; rep < 4; ++rep) {
            int idx = t + rep * 256;              // 1024
            int d = idx >> 3, c0 = (idx & 7) * 16;
            const float4* src = (const float4*)(Wq + d * 512 + h * 128 + c0);
            float4 v0 = src[0], v1 = src[1], v2 = src[2], v3 = src[3];
            short8 a, b;
            a[0]=f2bf(v0.x); a[1]=f2bf(v0.y); a[2]=f2bf(v0.z); a[3]=f2bf(v0.w);
            a[4]=f2bf(v1.x); a[5]=f2bf(v1.y); a[6]=f2bf(v1.z); a[7]=f2bf(v1.w);
            b[0]=f2bf(v2.x); b[1]=f2bf(v2.y); b[2]=f2bf(v2.z); b[3]=f2bf(v2.w);
            b[4]=f2bf(v3.x); b[5]=f2bf(v3.y); b[6]=f2bf(v3.z); b[7]=f2bf(v3.w);
            *(short8*)(L + d * PT + c0)     = a;
            *(short8*)(L + d * PT + c0 + 8) = b;
        }
        __syncthreads();

        // phase 3: MFMA — D[m=hid][n=d], K over c
        f32x4 acc[2][8];
        #pragma unroll
        for (int ml = 0; ml < 2; ++ml)
            #pragma unroll
            for (int nt2 = 0; nt2 < 8; ++nt2)
                acc[ml][nt2] = (f32x4){0.f, 0.f, 0.f, 0.f};
        #pragma unroll
        for (int ks = 0; ks < 4; ++ks) {
            short8 bfr[8];
            #pragma unroll
            for (int nt2 = 0; nt2 < 8; ++nt2)
                bfr[nt2] = *(const short8*)(L + (nt2*16 + l16) * PT + ks*32 + quad*8);
            #pragma unroll
            for (int ml = 0; ml < 2; ++ml)
                #pragma unroll
                for (int nt2 = 0; nt2 < 8; ++nt2)
                    acc[ml][nt2] = __builtin_amdgcn_mfma_f32_16x16x32_bf16(af[ml][ks], bfr[nt2], acc[ml][nt2], 0, 0, 0);
        }
        __syncthreads();

        // phase 4: C -> LDS bf16: L[hid*PT + d]
        #pragma unroll
        for (int ml = 0; ml < 2; ++ml)
            #pragma unroll
            for (int nt2 = 0; nt2 < 8; ++nt2)
                #pragma unroll
                for (int r = 0; r < 4; ++r)
                    L[((wv*2 + ml)*16 + quad*4 + r) * PT + nt2*16 + l16] = f2bf(acc[ml][nt2][r]);
        __syncthreads();

        // phase 5: frag-order readout -> A1F
        #pragma unroll
        for (int mt = 0; mt < 8; ++mt)
            #pragma unroll
            for (int ks = 0; ks < 4; ++ks) {
                short8 v = *(const short8*)(L + (mt*16 + l16) * PT + ks*32 + quad*8);
                *(short8*)(A1F + ((size_t)(((li*8 + mt)*4 + ks)*64 + lane)) * 8) = v;
            }
    } else {
        // =================== conversion path ===================
        for (int s = blk - 288; s < 1216; s += 896) {
            if (s < 1024) {
                int idx = s * 256 + t;            // [0,262144)
                const float4* x4 = (const float4*)x;
                float4 v0 = x4[idx * 2], v1 = x4[idx * 2 + 1];
                short8 sv;
                sv[0]=f2bf(v0.x); sv[1]=f2bf(v0.y); sv[2]=f2bf(v0.z); sv[3]=f2bf(v0.w);
                sv[4]=f2bf(v1.x); sv[5]=f2bf(v1.y); sv[6]=f2bf(v1.z); sv[7]=f2bf(v1.w);
                *(short8*)(xb + (size_t)idx * 8) = sv;
            } else if (s < 1152) {
                int r = (s - 1024) * 256 + t;     // [0,32768)
                int j = r & 7, lane = (r >> 3) & 63, ks = (r >> 9) & 3, mt = (r >> 11) & 1, e = r >> 12;
                int l16 = lane & 15, quad = lane >> 4;
                int m = mt * 16 + l16, k = ks * 32 + quad * 8 + j;
                W2F[r] = f2bf(W2[e * 4096 + k * 32 + m]);
            } else {
                out[(s - 1152) * 256 + t] = bout[0];  // [0,16384)
            }
        }
    }
}

// ---------------------------------------------------------------------------
// L2 K2B (R6-verbatim except cnt = cursors[li] directly): expert MLP.
//   GEMM1': h[hid][tok] = A1F[li] . xb^T  (128x64x128) relu+bias1 -> hL
//   GEMM2': o[od][tok]  = W2F[e]  . h^T   (32x64x128)  +b2
//   head:   out[b] += w * dot(o, Wout[h*32..))   (atomic)
// ---------------------------------------------------------------------------
__global__ __launch_bounds__(256) void k2b_expert(
    const short* __restrict__ xb, const short* __restrict__ A1F,
    const float* __restrict__ bias1, const short* __restrict__ W2F, const float* __restrict__ b2,
    const int* __restrict__ cursors, const int* __restrict__ listIdx,
    const float* __restrict__ wts, const float* __restrict__ Wout,
    const float* __restrict__ blkPart, float* __restrict__ out)
{
    __shared__ short tokL[64 * PT];
    __shared__ short hL[64 * PT];
    __shared__ int   ids[64];
    __shared__ float wsl[64];
    __shared__ float red[16][16];
    __shared__ float fin[16];

    const int li = blockIdx.y;
    const int e  = li >> 2;
    const int h  = li & 3;
    const int t  = threadIdx.x;

    if (blockIdx.x == gridDim.x - 1 && li == NL - 1) {
        int chunk = t >> 4, col = t & 15;
        float v = 0.f;
        for (int i = 0; i < 16; ++i) v += blkPart[(chunk * 16 + i) * 16 + col];
        red[chunk][col] = v;
        __syncthreads();
        if (t < 16) {
            float s = 0.f;
            #pragma unroll
            for (int c = 0; c < 16; ++c) s += red[c][t];
            fin[t] = s;
        }
        __syncthreads();
        if (t == 0) {
            float aux = 0.f;
            const float invN = 1.f / (float)NN;
            for (int e2 = 0; e2 < EE; ++e2) aux += (fin[8 + e2] * invN) * (fin[e2] * invN);
            out[BB] = (float)EE * aux;
        }
    }

    int cnt = cursors[li];
    if (cnt > CAP2) cnt = CAP2;
    const int off = blockIdx.x * 64;
    if (off >= cnt) return;
    const int sb  = li * CAP2 + off;
    const int nt  = min(64, cnt - off);

    if (t < 64) {
        int a = listIdx[sb + min(t, nt - 1)];
        ids[t] = a >> 3;                       // b index (a = 8b + 2h + rank)
        wsl[t] = (t < nt) ? wts[a] : 0.f;
    }
    __syncthreads();

    #pragma unroll
    for (int r = 0; r < 4; ++r) {
        int i = t + r * 256;
        int slot = i >> 4, seg = i & 15;
        short8 v = *(const short8*)(xb + (size_t)ids[slot] * 128 + seg * 8);
        *(short8*)(tokL + slot * PT + seg * 8) = v;
    }
    __syncthreads();

    const int wv   = t >> 6;
    const int lane = t & 63;
    const int l16  = lane & 15;
    const int quad = lane >> 4;

    // ---- GEMM1' ----
    f32x4 acc[2][4];
    #pragma unroll
    for (int ml = 0; ml < 2; ++ml)
        #pragma unroll
        for (int nl = 0; nl < 4; ++nl)
            acc[ml][nl] = (f32x4){0.f, 0.f, 0.f, 0.f};

    short8 af[2][4];
    #pragma unroll
    for (int ml = 0; ml < 2; ++ml)
        #pragma unroll
        for (int ks = 0; ks < 4; ++ks)
            af[ml][ks] = *(const short8*)(A1F + ((size_t)(((li*8 + wv*2 + ml)*4 + ks)*64 + lane)) * 8);

    short8 bfr[4][4];
    #pragma unroll
    for (int nl = 0; nl < 4; ++nl)
        #pragma unroll
        for (int ks = 0; ks < 4; ++ks)
            bfr[nl][ks] = *(const short8*)(tokL + (nl*16 + l16) * PT + ks*32 + quad*8);

    #pragma unroll
    for (int ks = 0; ks < 4; ++ks)
        #pragma unroll
        for (int ml = 0; ml < 2; ++ml)
            #pragma unroll
            for (int nl = 0; nl < 4; ++nl)
                acc[ml][nl] = __builtin_amdgcn_mfma_f32_16x16x32_bf16(af[ml][ks], bfr[nl][ks], acc[ml][nl], 0, 0, 0);

    #pragma unroll
    for (int ml = 0; ml < 2; ++ml) {
        int hid0 = wv*32 + ml*16 + quad*4;
        f32x4 b1v = *(const f32x4*)(bias1 + li*128 + hid0);
        #pragma unroll
        for (int nl = 0; nl < 4; ++nl) {
            short4v hv;
            #pragma unroll
            for (int r = 0; r < 4; ++r) {
                float v = acc[ml][nl][r] + b1v[r];
                hv[r] = f2bf(fmaxf(v, 0.f));
            }
            *(short4v*)(hL + (nl*16 + l16) * PT + hid0) = hv;
        }
    }
    __syncthreads();

    // ---- GEMM2' ----
    f32x4 acc2[2];
    acc2[0] = (f32x4){0.f, 0.f, 0.f, 0.f};
    acc2[1] = (f32x4){0.f, 0.f, 0.f, 0.f};

    short8 af2[2][4];
    #pragma unroll
    for (int ml = 0; ml < 2; ++ml)
        #pragma unroll
        for (int ks = 0; ks < 4; ++ks)
            af2[ml][ks] = *(const short8*)(W2F + ((size_t)(((e*2 + ml)*4 + ks)*64 + lane)) * 8);

    short8 bf2[4];
    #pragma unroll
    for (int ks = 0; ks < 4; ++ks)
        bf2[ks] = *(const short8*)(hL + (wv*16 + l16) * PT + ks*32 + quad*8);

    #pragma unroll
    for (int ks = 0; ks < 4; ++ks)
        #pragma unroll
        for (int ml = 0; ml < 2; ++ml)
            acc2[ml] = __builtin_amdgcn_mfma_f32_16x16x32_bf16(af2[ml][ks], bf2[ks], acc2[ml], 0, 0, 0);

    // ---- fused head (h uniform per block) ----
    const int slot = wv*16 + l16;
    const int b    = ids[slot];
    float partial = 0.f;
    #pragma unroll
    for (int ml = 0; ml < 2; ++ml) {
        int od0 = ml*16 + quad*4;
        f32x4 b2v = *(const f32x4*)(b2 + e*32 + od0);
        f32x4 wv4 = *(const f32x4*)(Wout + h*32 + od0);
        #pragma unroll
        for (int r = 0; r < 4; ++r)
            partial += (acc2[ml][r] + b2v[r]) * wv4[r];
    }
    partial += __shfl_xor(partial, 16);
    partial += __shfl_xor(partial, 32);
    if (quad == 0) {
        float v = partial * wsl[slot];
        atomicAdd(&out[b], v);
    }
}

extern "C" void kernel_launch(void* const* d_in, const int* in_sizes, int n_in,
                              void* d_out, int out_size, void* d_ws, size_t ws_size,
                              hipStream_t stream) {
    (void)in_sizes; (void)n_in; (void)out_size; (void)ws_size;
    const float* x    = (const float*)d_in[0];
    const float* Wq   = (const float*)d_in[1];
    const float* bq   = (const float*)d_in[2];
    const float* Wk   = (const float*)d_in[3];
    const float* bk   = (const float*)d_in[4];
    const float* Wg   = (const float*)d_in[5];
    const float* W1   = (const float*)d_in[6];
    const float* b1   = (const float*)d_in[7];
    const float* W2   = (const float*)d_in[8];
    const float* b2   = (const float*)d_in[9];
    const float* Wout = (const float*)d_in[10];
    const float* bout = (const float*)d_in[11];
    float* out = (float*)d_out;

    char* ws = (char*)d_ws;
    short* xb       = (short*)(ws + 0);              //  4,194,304
    float* wts      = (float*)(ws + 4194304);        //    524,288
    int*   listIdx  = (int*)  (ws + 4718592);        //    786,432 (32*CAP2*4)
    short* A1F      = (short*)(ws + 5505024);        //  1,048,576
    short* W2F      = (short*)(ws + 6553600);        //     65,536
    float* bias1    = (float*)(ws + 6635648);        //     16,384
    float* blkPart  = (float*)(ws + 6652032);        //     16,384
    int*   cursors  = (int*)  (ws + 6668416);        //        128

    hipMemsetAsync(cursors, 0, NL * sizeof(int), stream);
    mid<<<1184, 256, 0, stream>>>(x, Wq, bq, Wk, Wg, bk, W1, b1, W2, bout,
                                  xb, A1F, bias1, W2F, wts, blkPart, cursors, listIdx, out);
    k2b_expert<<<dim3(96, NL), 256, 0, stream>>>(xb, A1F, bias1, W2F, b2,
                                  cursors, listIdx, wts, Wout, blkPart, out);
}